// Round 11
// baseline (2665.142 us; speedup 1.0000x reference)
//
#include <hip/hip_runtime.h>
#include <stdint.h>
#include <math.h>

#define NPTS  8192
#define NB    2
#define NC    64
#define MCENT 2048
#define HH    128
#define K2NN  32

// float offsets inside d_out (outputs concatenated flat, all read as fp32)
#define OUT0_OFF 0                                   // dsamp_xyz (B,M,3)
#define OUT1_OFF (NB*MCENT*3)                        // shifted   (B,2M,3)
#define OUT2_OFF (OUT1_OFF + NB*2*MCENT*3)           // feats     (B,2*O,M)
#define OUT3_OFF (OUT2_OFF + NB*2*HH*MCENT)          // idx       (B,M) as float

__device__ __forceinline__ float silu_f(float v){ return v / (1.0f + expf(-v)); }

// ---- LDS-free full-wave reduce: DPP xor1/2/4/8 + row_bcast15/31 + readlane.
// update_dpp with old=v -> untargeted lanes keep v (identity for max/min).
template<int CTRL>
__device__ __forceinline__ unsigned dppk(unsigned v){
  return (unsigned)__builtin_amdgcn_update_dpp((int)v, (int)v, CTRL, 0xF, 0xF, false);
}
__device__ __forceinline__ unsigned wave_max_u32_sgpr(unsigned v){
  unsigned s;
  s = dppk<0xB1>(v);  v = v > s ? v : s;   // quad_perm xor1
  s = dppk<0x4E>(v);  v = v > s ? v : s;   // quad_perm xor2
  s = dppk<0x141>(v); v = v > s ? v : s;   // row_half_mirror (xor4)
  s = dppk<0x140>(v); v = v > s ? v : s;   // row_mirror      (xor8)
  s = dppk<0x142>(v); v = v > s ? v : s;   // row_bcast15
  s = dppk<0x143>(v); v = v > s ? v : s;   // row_bcast31 -> lane63 full wave
  return (unsigned)__builtin_amdgcn_readlane((int)v, 63);  // uniform (SGPR)
}
__device__ __forceinline__ unsigned wave_min_u32_sgpr(unsigned v){
  unsigned s;
  s = dppk<0xB1>(v);  v = v < s ? v : s;
  s = dppk<0x4E>(v);  v = v < s ? v : s;
  s = dppk<0x141>(v); v = v < s ? v : s;
  s = dppk<0x140>(v); v = v < s ? v : s;
  s = dppk<0x142>(v); v = v < s ? v : s;
  s = dppk<0x143>(v); v = v < s ? v : s;
  return (unsigned)__builtin_amdgcn_readlane((int)v, 63);
}

// LDS-only barrier: order LDS producer->consumer across the block WITHOUT
// draining the vector-memory store queue (publish stores stay in flight;
// never read back in-kernel; kernel-end drain covers later kernels).
__device__ __forceinline__ void bar_lds(){
  asm volatile("s_waitcnt lgkmcnt(0)" ::: "memory");
  __builtin_amdgcn_s_barrier();
  __builtin_amdgcn_sched_barrier(0);
}

// ---------------------------------------------------------------------------
// Kernel 1: farthest point sampling. One block per batch, 1024 thr x 8 pts in
// registers (16 waves/CU = 4/SIMD: TLP hides reduce/LDS/broadcast latency and
// shrinks barrier skew; per-SIMD VALU issue is invariant). 96KB LDS mirror for
// winner broadcast, one LDS-only barrier/iter, DPP+readlane wave reduce.
// Exact reference semantics: contract off, numpy op order, first-max index
// (ballot lowest lane = lowest point under blocked assignment; u64 block key).
// ---------------------------------------------------------------------------
__global__ __launch_bounds__(1024, 4) void fps_kernel(const float* __restrict__ xyz,
                                                      float* __restrict__ out,
                                                      int* __restrict__ ws_idx){
#pragma clang fp contract(off)
  __shared__ float xs[NPTS], ys[NPTS], zs[NPTS];      // 96 KB mirror
  __shared__ unsigned long long warr[2][16];
  const int b    = blockIdx.x;
  const int tid  = threadIdx.x;
  const int lane = tid & 63, wid = tid >> 6;
  const float* P = xyz + (size_t)b * NPTS * 3;

  float x[8], y[8], z[8], mind[8];
  #pragma unroll
  for (int j = 0; j < 8; ++j){
    const int p = tid*8 + j;
    const float px = P[p*3+0], py = P[p*3+1], pz = P[p*3+2];
    x[j] = px; y[j] = py; z[j] = pz; mind[j] = 1e10f;
    xs[p] = px; ys[p] = py; zs[p] = pz;
  }
  float cx = P[0], cy = P[1], cz = P[2];
  if (tid == 0){
    ws_idx[b*MCENT] = 0;
    out[OUT3_OFF + b*MCENT] = 0.0f;
    out[OUT0_OFF + (size_t)(b*MCENT)*3 + 0] = cx;
    out[OUT0_OFF + (size_t)(b*MCENT)*3 + 1] = cy;
    out[OUT0_OFF + (size_t)(b*MCENT)*3 + 2] = cz;
  }
  __syncthreads();

  for (int t = 1; t < MCENT; ++t){
    // ---- distance + min update + running first-argmax (reference op order)
    float bestv = -1.0f; int bestp = tid*8;
    #pragma unroll
    for (int j = 0; j < 8; ++j){
      const float dx = x[j]-cx, dy = y[j]-cy, dz = z[j]-cz;
      const float d  = (dx*dx + dy*dy) + dz*dz;   // contract off: per-op rounding
      const float mn = fminf(mind[j], d);
      mind[j] = mn;
      if (mn > bestv){ bestv = mn; bestp = tid*8 + j; }   // strict > keeps first
    }
    // ---- LDS-free wave reduce (bestv>=0 -> u32 order == f32 order)
    const unsigned vb = __float_as_uint(bestv);
    const unsigned wv = wave_max_u32_sgpr(vb);            // SGPR broadcast
    const unsigned long long bal = __ballot(vb == wv);
    const int wl = __ffsll(bal) - 1;                      // lowest lane = lowest p
    const int wp = __builtin_amdgcn_readlane(bestp, wl);  // SGPR, no bpermute
    if (lane == 0)
      warr[t & 1][wid] = ((unsigned long long)wv << 32) | (unsigned)(NPTS-1-wp);
    bar_lds();                                    // only barrier in the loop
    // ---- block reduce over 16 wave keys (ties -> larger (N-1-p) = smaller p)
    unsigned long long kb = warr[t & 1][0];
    #pragma unroll
    for (int w = 1; w < 16; ++w){
      const unsigned long long k2 = warr[t & 1][w];
      if (k2 > kb) kb = k2;
    }
    const int p = NPTS - 1 - (int)(kb & 0xFFFFFFFFULL);
    cx = xs[p]; cy = ys[p]; cz = zs[p];           // uniform broadcast reads
    if (tid == 0){                                 // fire-and-forget publishes
      ws_idx[b*MCENT + t] = p;
      out[OUT3_OFF + b*MCENT + t] = (float)p;
      out[OUT0_OFF + (size_t)(b*MCENT + t)*3 + 0] = cx;
      out[OUT0_OFF + (size_t)(b*MCENT + t)*3 + 1] = cy;
      out[OUT0_OFF + (size_t)(b*MCENT + t)*3 + 2] = cz;
    }
  }
}

// ---------------------------------------------------------------------------
// Kernel 2: exact 32-NN per center, ascending by (d2, idx); first 16 = 16-NN.
// Per-thread top-2 cache; LDS-free value min-reduce. (r10 proven, unchanged)
// ---------------------------------------------------------------------------
__global__ __launch_bounds__(256) void knn_kernel(const float* __restrict__ xyz,
                                                  const float* __restrict__ out,
                                                  int* __restrict__ ws_knn){
#pragma clang fp contract(off)
  __shared__ unsigned d2u[NPTS];          // monotonic-transformed d2 bits
  __shared__ unsigned long long warr[2][4];
  const int blk = blockIdx.x;
  const int b = blk / MCENT, m = blk % MCENT;
  const int tid = threadIdx.x;
  const float* P = xyz + (size_t)b*NPTS*3;
  const float cx = out[OUT0_OFF + (size_t)(b*MCENT+m)*3 + 0];
  const float cy = out[OUT0_OFF + (size_t)(b*MCENT+m)*3 + 1];
  const float cz = out[OUT0_OFF + (size_t)(b*MCENT+m)*3 + 2];
  const float cn = (cx*cx + cy*cy) + cz*cz;

  unsigned long long best = ~0ULL, second = ~0ULL;
  #pragma unroll 4
  for (int j = 0; j < NPTS/256; ++j){
    const int p = tid + 256*j;
    const float px = P[p*3+0], py = P[p*3+1], pz = P[p*3+2];
    const float pn = (px*px + py*py) + pz*pz;
    const float e  = (cx*px + cy*py) + cz*pz;
    const float d2 = (cn + pn) - 2.0f*e;           // reference formula / op order
    unsigned u = __float_as_uint(d2);
    u = (u & 0x80000000u) ? ~u : (u | 0x80000000u);
    d2u[p] = u;
    const unsigned long long kk = ((unsigned long long)u << 32) | (unsigned)p;
    if      (kk < best)  { second = best; best = kk; }
    else if (kk < second){ second = kk; }
  }
  __syncthreads();

  for (int it = 0; it < K2NN; ++it){
    const unsigned vb = (unsigned)(best >> 32);
    const unsigned wv = wave_min_u32_sgpr(vb);
    const unsigned long long bal = __ballot(vb == wv);
    unsigned long long k;
    if (__popcll(bal) == 1){
      const int wl = __ffsll(bal) - 1;
      const unsigned lp = (unsigned)__builtin_amdgcn_readlane((int)(unsigned)best, wl);
      k = ((unsigned long long)wv << 32) | lp;     // low32 = p
    } else {
      // exact fallback: u64 (value,idx) min butterfly (rare value tie in wave)
      k = best;
      #pragma unroll
      for (int o = 32; o > 0; o >>= 1){
        const unsigned long long k2 = __shfl_xor(k, o);
        if (k2 < k) k = k2;
      }
    }
    if ((tid & 63) == 0) warr[it & 1][tid >> 6] = k;
    __syncthreads();
    unsigned long long kb = warr[it & 1][0];
    #pragma unroll
    for (int w = 1; w < 4; ++w){
      const unsigned long long k2 = warr[it & 1][w];
      if (k2 < kb) kb = k2;                        // u64 min: ties pick min p
    }
    const unsigned p = (unsigned)kb;
    if (tid == 0) ws_knn[(size_t)blk*K2NN + it] = (int)p;
    if (best == kb){                               // unique owner (keys unique by p)
      d2u[p] = 0xFFFFFFFFu;                        // mark removed (own partition)
      best = second; second = ~0ULL;
      if (best == ~0ULL){                          // top-2 exhausted: rescan own part
        #pragma unroll 4
        for (int j = 0; j < NPTS/256; ++j){
          const int q = tid + 256*j;
          const unsigned long long kk = ((unsigned long long)d2u[q] << 32) | (unsigned)q;
          if      (kk < best)  { second = best; best = kk; }
          else if (kk < second){ second = kk; }
        }
      }
    }
  }
}

// ---------------------------------------------------------------------------
// Kernel 3: fused EGNN per (b,m) (round-2 proven, unchanged).
// ---------------------------------------------------------------------------
#define S1STR 132   // padded row stride: 16B-aligned float4, decorrelated banks

template<int KNB>
__device__ __forceinline__ void egnn_scale(
    int isc, int b, int m, int tid,
    const float* __restrict__ we1, const float* __restrict__ be1,
    const float* __restrict__ we2, const float* __restrict__ be2,
    const float* __restrict__ wxw, const float* __restrict__ bxw,
    const float* __restrict__ wh1, const float* __restrict__ bh1,
    const float* __restrict__ wh2, const float* __restrict__ bh2,
    const float* hi, const float (*hj)[NC], const float (*rel)[3],
    const float* d2s, float (*s1)[S1STR], float (*s2)[S1STR],
    float* coefs, float* aggs, float* t1,
    float cx, float cy, float cz, float* __restrict__ out)
{
  constexpr int KH = KNB/2;
  const int h  = tid & 127;
  const int jg = tid >> 7;
  const int j0 = jg * KH;
  const float* W1 = we1 + (size_t)isc*129*HH;
  const float* W2 = we2 + (size_t)isc*HH*HH;

  // ---- edge layer 1: [h_i, h_j, d2] @ we1 + be1, silu
  float shi = be1[isc*HH + h];
  for (int r = 0; r < NC; ++r) shi += hi[r] * W1[r*HH + h];   // h_i part: shared by all j
  float acc[KH];
  #pragma unroll
  for (int jl = 0; jl < KH; ++jl) acc[jl] = shi;
  for (int r4 = 0; r4 < NC/4; ++r4){
    const float w0 = W1[(NC + 4*r4+0)*HH + h];
    const float w1 = W1[(NC + 4*r4+1)*HH + h];
    const float w2 = W1[(NC + 4*r4+2)*HH + h];
    const float w3 = W1[(NC + 4*r4+3)*HH + h];
    #pragma unroll
    for (int jl = 0; jl < KH; ++jl){
      const float4 v = *(const float4*)&hj[j0+jl][4*r4];
      acc[jl] += v.x*w0; acc[jl] += v.y*w1; acc[jl] += v.z*w2; acc[jl] += v.w*w3;
    }
  }
  {
    const float wd = W1[128*HH + h];
    #pragma unroll
    for (int jl = 0; jl < KH; ++jl)
      s1[j0+jl][h] = silu_f(acc[jl] + d2s[j0+jl]*wd);
  }
  __syncthreads();

  // ---- edge layer 2: @ we2 + be2, silu
  float acc2[KH];
  {
    const float b2 = be2[isc*HH + h];
    #pragma unroll
    for (int jl = 0; jl < KH; ++jl) acc2[jl] = b2;
  }
  for (int r4 = 0; r4 < HH/4; ++r4){
    const float w0 = W2[(4*r4+0)*HH + h];
    const float w1 = W2[(4*r4+1)*HH + h];
    const float w2 = W2[(4*r4+2)*HH + h];
    const float w3 = W2[(4*r4+3)*HH + h];
    #pragma unroll
    for (int jl = 0; jl < KH; ++jl){
      const float4 v = *(const float4*)&s1[j0+jl][4*r4];
      acc2[jl] += v.x*w0; acc2[jl] += v.y*w1; acc2[jl] += v.z*w2; acc2[jl] += v.w*w3;
    }
  }
  #pragma unroll
  for (int jl = 0; jl < KH; ++jl)
    s2[j0+jl][h] = silu_f(acc2[jl]);
  __syncthreads();

  // ---- agg over j (threads 0..127) and coef per j (threads 128..128+KNB)
  if (tid < HH){
    float a = 0.f;
    #pragma unroll
    for (int j = 0; j < KNB; ++j) a += s2[j][tid];
    aggs[tid] = a;
  } else if (tid < HH + KNB){
    const int j = tid - HH;
    const float* WX = wxw + isc*HH;
    float c = 0.f;
    for (int r = 0; r < HH; ++r) c += s2[j][r]*WX[r];
    coefs[j] = c + bxw[isc];
  }
  __syncthreads();

  // ---- coordinate shift output
  if (tid < 3){
    float s = 0.f;
    #pragma unroll
    for (int j = 0; j < KNB; ++j) s += rel[j][tid]*coefs[j];
    const float cc = (tid==0) ? cx : ((tid==1) ? cy : cz);
    out[OUT1_OFF + ((size_t)(b*2 + isc)*MCENT + m)*3 + tid] = cc + s*(1.0f/KNB);
  }

  // ---- node MLP layer 1: [h_i, agg] @ wh1 + bh1, silu
  if (tid < HH){
    const float* WH1 = wh1 + (size_t)isc*(NC+HH)*HH;
    float n = bh1[isc*HH + tid];
    for (int r = 0; r < NC; ++r) n += hi[r]*WH1[r*HH + tid];
    for (int r = 0; r < HH; ++r) n += aggs[r]*WH1[(NC+r)*HH + tid];
    t1[tid] = silu_f(n);
  }
  __syncthreads();

  // ---- node MLP layer 2 (no activation)
  if (tid < HH){
    const float* WH2 = wh2 + (size_t)isc*HH*HH;
    float v = bh2[isc*HH + tid];
    for (int r = 0; r < HH; ++r) v += t1[r]*WH2[r*HH + tid];
    out[OUT2_OFF + ((size_t)(b*2*HH) + isc*HH + tid)*MCENT + m] = v;
  }
  __syncthreads();  // before next scale reuses s1/s2/aggs/t1/coefs
}

__global__ __launch_bounds__(256) void egnn_kernel(
    const float* __restrict__ xyz,  const float* __restrict__ feat,
    const float* __restrict__ we1,  const float* __restrict__ be1,
    const float* __restrict__ we2,  const float* __restrict__ be2,
    const float* __restrict__ wxw,  const float* __restrict__ bxw,
    const float* __restrict__ wh1,  const float* __restrict__ bh1,
    const float* __restrict__ wh2,  const float* __restrict__ bh2,
    const int* __restrict__ ws_idx, const int* __restrict__ ws_knn,
    float* __restrict__ out)
{
  __shared__ __align__(16) float hi[NC];
  __shared__ __align__(16) float hj[K2NN][NC];
  __shared__ float rel[K2NN][3];
  __shared__ float d2s[K2NN];
  __shared__ __align__(16) float s1[K2NN][S1STR];
  __shared__ __align__(16) float s2[K2NN][S1STR];
  __shared__ float coefs[K2NN];
  __shared__ float aggs[HH];
  __shared__ float t1[HH];
  __shared__ int   nidx[K2NN];

  const int blk = blockIdx.x;
  const int b = blk / MCENT, m = blk % MCENT;
  const int tid = threadIdx.x;
  const float* P = xyz + (size_t)b*NPTS*3;
  const float cx = out[OUT0_OFF + (size_t)(b*MCENT+m)*3 + 0];
  const float cy = out[OUT0_OFF + (size_t)(b*MCENT+m)*3 + 1];
  const float cz = out[OUT0_OFF + (size_t)(b*MCENT+m)*3 + 2];

  const int ci = ws_idx[b*MCENT + m];
  if (tid < NC)   hi[tid]   = feat[((size_t)b*NC + tid)*NPTS + ci];
  if (tid < K2NN) nidx[tid] = ws_knn[(size_t)blk*K2NN + tid];
  __syncthreads();

  if (tid < K2NN){
    const int p = nidx[tid];
    const float rx = cx - P[p*3+0];
    const float ry = cy - P[p*3+1];
    const float rz = cz - P[p*3+2];
    rel[tid][0]=rx; rel[tid][1]=ry; rel[tid][2]=rz;
    d2s[tid] = rx*rx + ry*ry + rz*rz;
  }
  {
    const int j  = tid >> 3;
    const int c0 = (tid & 7) * 8;
    const int p  = nidx[j];
    #pragma unroll
    for (int q = 0; q < 8; ++q)
      hj[j][c0+q] = feat[((size_t)b*NC + c0 + q)*NPTS + p];
  }
  __syncthreads();

  egnn_scale<16>(0, b, m, tid, we1, be1, we2, be2, wxw, bxw, wh1, bh1, wh2, bh2,
                 hi, hj, rel, d2s, s1, s2, coefs, aggs, t1, cx, cy, cz, out);
  egnn_scale<32>(1, b, m, tid, we1, be1, we2, be2, wxw, bxw, wh1, bh1, wh2, bh2,
                 hi, hj, rel, d2s, s1, s2, coefs, aggs, t1, cx, cy, cz, out);
}

// ---------------------------------------------------------------------------
extern "C" void kernel_launch(void* const* d_in, const int* in_sizes, int n_in,
                              void* d_out, int out_size, void* d_ws, size_t ws_size,
                              hipStream_t stream){
  const float* xyz = (const float*)d_in[0];
  const float* feat= (const float*)d_in[1];
  const float* we1 = (const float*)d_in[2];
  const float* be1 = (const float*)d_in[3];
  const float* we2 = (const float*)d_in[4];
  const float* be2 = (const float*)d_in[5];
  const float* wxw = (const float*)d_in[6];
  const float* bxw = (const float*)d_in[7];
  const float* wh1 = (const float*)d_in[8];
  const float* bh1 = (const float*)d_in[9];
  const float* wh2 = (const float*)d_in[10];
  const float* bh2 = (const float*)d_in[11];
  float* out = (float*)d_out;

  // workspace: idx (B*M int) + knn (B*M*32 int) = 528 KB
  int* ws_idx = (int*)d_ws;
  int* ws_knn = ws_idx + NB*MCENT;

  fps_kernel <<<dim3(NB),        dim3(1024), 0, stream>>>(xyz, out, ws_idx);
  knn_kernel <<<dim3(NB*MCENT),  dim3(256),  0, stream>>>(xyz, out, ws_knn);
  egnn_kernel<<<dim3(NB*MCENT),  dim3(256),  0, stream>>>(xyz, feat,
      we1, be1, we2, be2, wxw, bxw, wh1, bh1, wh2, bh2, ws_idx, ws_knn, out);
}

// Round 12
// 2301.112 us; speedup vs baseline: 1.1582x; 1.1582x over previous
//
#include <hip/hip_runtime.h>
#include <stdint.h>
#include <math.h>

#define NPTS  8192
#define NB    2
#define NC    64
#define MCENT 2048
#define HH    128
#define K2NN  32

// float offsets inside d_out (outputs concatenated flat, all read as fp32)
#define OUT0_OFF 0                                   // dsamp_xyz (B,M,3)
#define OUT1_OFF (NB*MCENT*3)                        // shifted   (B,2M,3)
#define OUT2_OFF (OUT1_OFF + NB*2*MCENT*3)           // feats     (B,2*O,M)
#define OUT3_OFF (OUT2_OFF + NB*2*HH*MCENT)          // idx       (B,M) as float

__device__ __forceinline__ float silu_f(float v){ return v / (1.0f + expf(-v)); }

// ---- LDS-free full-wave reduce: DPP xor1/2/4/8 + row_bcast15/31 + readlane.
// update_dpp with old=v -> untargeted lanes keep v (identity for max/min).
template<int CTRL>
__device__ __forceinline__ unsigned dppk(unsigned v){
  return (unsigned)__builtin_amdgcn_update_dpp((int)v, (int)v, CTRL, 0xF, 0xF, false);
}
__device__ __forceinline__ unsigned wave_max_u32_sgpr(unsigned v){
  unsigned s;
  s = dppk<0xB1>(v);  v = v > s ? v : s;   // quad_perm xor1
  s = dppk<0x4E>(v);  v = v > s ? v : s;   // quad_perm xor2
  s = dppk<0x141>(v); v = v > s ? v : s;   // row_half_mirror (xor4)
  s = dppk<0x140>(v); v = v > s ? v : s;   // row_mirror      (xor8)
  s = dppk<0x142>(v); v = v > s ? v : s;   // row_bcast15
  s = dppk<0x143>(v); v = v > s ? v : s;   // row_bcast31 -> lane63 full wave
  return (unsigned)__builtin_amdgcn_readlane((int)v, 63);  // uniform (SGPR)
}
__device__ __forceinline__ unsigned wave_min_u32_sgpr(unsigned v){
  unsigned s;
  s = dppk<0xB1>(v);  v = v < s ? v : s;
  s = dppk<0x4E>(v);  v = v < s ? v : s;
  s = dppk<0x141>(v); v = v < s ? v : s;
  s = dppk<0x140>(v); v = v < s ? v : s;
  s = dppk<0x142>(v); v = v < s ? v : s;
  s = dppk<0x143>(v); v = v < s ? v : s;
  return (unsigned)__builtin_amdgcn_readlane((int)v, 63);
}

// LDS-only barrier: order LDS producer->consumer across the block WITHOUT
// draining the vector-memory store queue (publish stores stay in flight;
// never read back in-kernel; kernel-end drain covers later kernels).
__device__ __forceinline__ void bar_lds(){
  asm volatile("s_waitcnt lgkmcnt(0)" ::: "memory");
  __builtin_amdgcn_s_barrier();
  __builtin_amdgcn_sched_barrier(0);
}

// ---------------------------------------------------------------------------
// Kernel 1: farthest point sampling. One block per batch, 256 thr x 32 pts in
// registers (4 waves = 1/SIMD: minimal barrier skew + no redundant cross-wave
// reduce work; per-SIMD VALU issue floor is invariant to the split). 96KB LDS
// mirror for winner broadcast, one LDS-only barrier/iter, DPP+readlane reduce.
// Exact reference semantics: contract off, numpy op order, first-max index
// (ballot lowest lane = lowest point under blocked assignment; u64 block key).
// ---------------------------------------------------------------------------
__global__ __launch_bounds__(256, 2) void fps_kernel(const float* __restrict__ xyz,
                                                     float* __restrict__ out,
                                                     int* __restrict__ ws_idx){
#pragma clang fp contract(off)
  __shared__ float xs[NPTS], ys[NPTS], zs[NPTS];      // 96 KB mirror
  __shared__ unsigned long long warr[2][4];
  const int b    = blockIdx.x;
  const int tid  = threadIdx.x;
  const int lane = tid & 63, wid = tid >> 6;
  const float* P = xyz + (size_t)b * NPTS * 3;

  float x[32], y[32], z[32], mind[32];
  #pragma unroll
  for (int j = 0; j < 32; ++j){
    const int p = tid*32 + j;
    const float px = P[p*3+0], py = P[p*3+1], pz = P[p*3+2];
    x[j] = px; y[j] = py; z[j] = pz; mind[j] = 1e10f;
    xs[p] = px; ys[p] = py; zs[p] = pz;
  }
  float cx = P[0], cy = P[1], cz = P[2];
  if (tid == 0){
    ws_idx[b*MCENT] = 0;
    out[OUT3_OFF + b*MCENT] = 0.0f;
    out[OUT0_OFF + (size_t)(b*MCENT)*3 + 0] = cx;
    out[OUT0_OFF + (size_t)(b*MCENT)*3 + 1] = cy;
    out[OUT0_OFF + (size_t)(b*MCENT)*3 + 2] = cz;
  }
  __syncthreads();

  for (int t = 1; t < MCENT; ++t){
    // ---- distance + min update + running first-argmax (reference op order)
    float bestv = -1.0f; int bestp = tid*32;
    #pragma unroll
    for (int j = 0; j < 32; ++j){
      const float dx = x[j]-cx, dy = y[j]-cy, dz = z[j]-cz;
      const float d  = (dx*dx + dy*dy) + dz*dz;   // contract off: per-op rounding
      const float mn = fminf(mind[j], d);
      mind[j] = mn;
      if (mn > bestv){ bestv = mn; bestp = tid*32 + j; }  // strict > keeps first
    }
    // ---- LDS-free wave reduce (bestv>=0 -> u32 order == f32 order)
    const unsigned vb = __float_as_uint(bestv);
    const unsigned wv = wave_max_u32_sgpr(vb);            // SGPR broadcast
    const unsigned long long bal = __ballot(vb == wv);
    const int wl = __ffsll(bal) - 1;                      // lowest lane = lowest p
    const int wp = __builtin_amdgcn_readlane(bestp, wl);  // SGPR, no bpermute
    if (lane == 0)
      warr[t & 1][wid] = ((unsigned long long)wv << 32) | (unsigned)(NPTS-1-wp);
    bar_lds();                                    // only barrier in the loop
    // ---- block reduce over 4 wave keys (ties -> larger (N-1-p) = smaller p)
    unsigned long long kb = warr[t & 1][0];
    #pragma unroll
    for (int w = 1; w < 4; ++w){
      const unsigned long long k2 = warr[t & 1][w];
      if (k2 > kb) kb = k2;
    }
    const int p = NPTS - 1 - (int)(kb & 0xFFFFFFFFULL);
    cx = xs[p]; cy = ys[p]; cz = zs[p];           // uniform broadcast reads
    if (tid == 0){                                 // fire-and-forget publishes
      ws_idx[b*MCENT + t] = p;
      out[OUT3_OFF + b*MCENT + t] = (float)p;
      out[OUT0_OFF + (size_t)(b*MCENT + t)*3 + 0] = cx;
      out[OUT0_OFF + (size_t)(b*MCENT + t)*3 + 1] = cy;
      out[OUT0_OFF + (size_t)(b*MCENT + t)*3 + 2] = cz;
    }
  }
}

// ---------------------------------------------------------------------------
// Kernel 2: fused KNN + EGNN per (b,m). Phase A: exact 32-NN ascending by
// (d2, idx) -> nidx in LDS (no global round-trip). Phase B: gather + edge
// MLP x2 + coord/feat heads (r2-proven bodies). d2u region is reused by
// s1/s2 after Phase A (barrier-separated).
// ---------------------------------------------------------------------------
#define S1STR 132
// LDS union layout (bytes)
#define C_D2U   0        // u32 x 8192 (Phase A) -- aliased by s1/s2 in Phase B
#define C_S1    0        // float[32][132]
#define C_S2    16896    // float[32][132]
#define C_HJ    33792    // float[32][64]
#define C_HI    41984    // float[64]
#define C_REL   42240    // float[32][3]
#define C_D2S   42624    // float[32]
#define C_AGG   42752    // float[128]
#define C_T1    43264    // float[128]
#define C_COEF  43776    // float[32]
#define C_NIDX  43904    // int[32]
#define C_WARR  44032    // u64[2][4]
#define C_SIZE  44096

template<int KNB>
__device__ __forceinline__ void egnn_scale(
    int isc, int b, int m, int tid,
    const float* __restrict__ we1, const float* __restrict__ be1,
    const float* __restrict__ we2, const float* __restrict__ be2,
    const float* __restrict__ wxw, const float* __restrict__ bxw,
    const float* __restrict__ wh1, const float* __restrict__ bh1,
    const float* __restrict__ wh2, const float* __restrict__ bh2,
    const float* hi, const float (*hj)[NC], const float (*rel)[3],
    const float* d2s, float (*s1)[S1STR], float (*s2)[S1STR],
    float* coefs, float* aggs, float* t1,
    float cx, float cy, float cz, float* __restrict__ out)
{
  constexpr int KH = KNB/2;
  const int h  = tid & 127;
  const int jg = tid >> 7;
  const int j0 = jg * KH;
  const float* W1 = we1 + (size_t)isc*129*HH;
  const float* W2 = we2 + (size_t)isc*HH*HH;

  // ---- edge layer 1: [h_i, h_j, d2] @ we1 + be1, silu
  float shi = be1[isc*HH + h];
  for (int r = 0; r < NC; ++r) shi += hi[r] * W1[r*HH + h];   // h_i part: shared by all j
  float acc[KH];
  #pragma unroll
  for (int jl = 0; jl < KH; ++jl) acc[jl] = shi;
  for (int r4 = 0; r4 < NC/4; ++r4){
    const float w0 = W1[(NC + 4*r4+0)*HH + h];
    const float w1 = W1[(NC + 4*r4+1)*HH + h];
    const float w2 = W1[(NC + 4*r4+2)*HH + h];
    const float w3 = W1[(NC + 4*r4+3)*HH + h];
    #pragma unroll
    for (int jl = 0; jl < KH; ++jl){
      const float4 v = *(const float4*)&hj[j0+jl][4*r4];
      acc[jl] += v.x*w0; acc[jl] += v.y*w1; acc[jl] += v.z*w2; acc[jl] += v.w*w3;
    }
  }
  {
    const float wd = W1[128*HH + h];
    #pragma unroll
    for (int jl = 0; jl < KH; ++jl)
      s1[j0+jl][h] = silu_f(acc[jl] + d2s[j0+jl]*wd);
  }
  __syncthreads();

  // ---- edge layer 2: @ we2 + be2, silu
  float acc2[KH];
  {
    const float b2 = be2[isc*HH + h];
    #pragma unroll
    for (int jl = 0; jl < KH; ++jl) acc2[jl] = b2;
  }
  for (int r4 = 0; r4 < HH/4; ++r4){
    const float w0 = W2[(4*r4+0)*HH + h];
    const float w1 = W2[(4*r4+1)*HH + h];
    const float w2 = W2[(4*r4+2)*HH + h];
    const float w3 = W2[(4*r4+3)*HH + h];
    #pragma unroll
    for (int jl = 0; jl < KH; ++jl){
      const float4 v = *(const float4*)&s1[j0+jl][4*r4];
      acc2[jl] += v.x*w0; acc2[jl] += v.y*w1; acc2[jl] += v.z*w2; acc2[jl] += v.w*w3;
    }
  }
  #pragma unroll
  for (int jl = 0; jl < KH; ++jl)
    s2[j0+jl][h] = silu_f(acc2[jl]);
  __syncthreads();

  // ---- agg over j (threads 0..127) and coef per j (threads 128..128+KNB)
  if (tid < HH){
    float a = 0.f;
    #pragma unroll
    for (int j = 0; j < KNB; ++j) a += s2[j][tid];
    aggs[tid] = a;
  } else if (tid < HH + KNB){
    const int j = tid - HH;
    const float* WX = wxw + isc*HH;
    float c = 0.f;
    for (int r = 0; r < HH; ++r) c += s2[j][r]*WX[r];
    coefs[j] = c + bxw[isc];
  }
  __syncthreads();

  // ---- coordinate shift output
  if (tid < 3){
    float s = 0.f;
    #pragma unroll
    for (int j = 0; j < KNB; ++j) s += rel[j][tid]*coefs[j];
    const float cc = (tid==0) ? cx : ((tid==1) ? cy : cz);
    out[OUT1_OFF + ((size_t)(b*2 + isc)*MCENT + m)*3 + tid] = cc + s*(1.0f/KNB);
  }

  // ---- node MLP layer 1: [h_i, agg] @ wh1 + bh1, silu
  if (tid < HH){
    const float* WH1 = wh1 + (size_t)isc*(NC+HH)*HH;
    float n = bh1[isc*HH + tid];
    for (int r = 0; r < NC; ++r) n += hi[r]*WH1[r*HH + tid];
    for (int r = 0; r < HH; ++r) n += aggs[r]*WH1[(NC+r)*HH + tid];
    t1[tid] = silu_f(n);
  }
  __syncthreads();

  // ---- node MLP layer 2 (no activation)
  if (tid < HH){
    const float* WH2 = wh2 + (size_t)isc*HH*HH;
    float v = bh2[isc*HH + tid];
    for (int r = 0; r < HH; ++r) v += t1[r]*WH2[r*HH + tid];
    out[OUT2_OFF + ((size_t)(b*2*HH) + isc*HH + tid)*MCENT + m] = v;
  }
  __syncthreads();  // before next scale reuses s1/s2/aggs/t1/coefs
}

__global__ __launch_bounds__(256) void knn_egnn_kernel(
    const float* __restrict__ xyz,  const float* __restrict__ feat,
    const float* __restrict__ we1,  const float* __restrict__ be1,
    const float* __restrict__ we2,  const float* __restrict__ be2,
    const float* __restrict__ wxw,  const float* __restrict__ bxw,
    const float* __restrict__ wh1,  const float* __restrict__ bh1,
    const float* __restrict__ wh2,  const float* __restrict__ bh2,
    const int* __restrict__ ws_idx, float* __restrict__ out)
{
#pragma clang fp contract(off)
  __shared__ __align__(16) char smem[C_SIZE];
  unsigned* d2u = (unsigned*)(smem + C_D2U);
  float (*s1)[S1STR] = (float (*)[S1STR])(smem + C_S1);
  float (*s2)[S1STR] = (float (*)[S1STR])(smem + C_S2);
  float (*hj)[NC]    = (float (*)[NC])(smem + C_HJ);
  float* hi    = (float*)(smem + C_HI);
  float (*rel)[3] = (float (*)[3])(smem + C_REL);
  float* d2s   = (float*)(smem + C_D2S);
  float* aggs  = (float*)(smem + C_AGG);
  float* t1    = (float*)(smem + C_T1);
  float* coefs = (float*)(smem + C_COEF);
  int*   nidx  = (int*)(smem + C_NIDX);
  unsigned long long (*warr)[4] = (unsigned long long (*)[4])(smem + C_WARR);

  const int blk = blockIdx.x;
  const int b = blk / MCENT, m = blk % MCENT;
  const int tid = threadIdx.x;
  const float* P = xyz + (size_t)b*NPTS*3;
  const float cx = out[OUT0_OFF + (size_t)(b*MCENT+m)*3 + 0];
  const float cy = out[OUT0_OFF + (size_t)(b*MCENT+m)*3 + 1];
  const float cz = out[OUT0_OFF + (size_t)(b*MCENT+m)*3 + 2];

  // ================= Phase A: exact 32-NN (ascending by (d2, idx)) ========
  {
    const float cn = (cx*cx + cy*cy) + cz*cz;
    unsigned long long best = ~0ULL, second = ~0ULL;
    #pragma unroll 4
    for (int j = 0; j < NPTS/256; ++j){
      const int p = tid + 256*j;
      const float px = P[p*3+0], py = P[p*3+1], pz = P[p*3+2];
      const float pn = (px*px + py*py) + pz*pz;
      const float e  = (cx*px + cy*py) + cz*pz;
      const float d2 = (cn + pn) - 2.0f*e;           // reference formula / op order
      unsigned u = __float_as_uint(d2);
      u = (u & 0x80000000u) ? ~u : (u | 0x80000000u);
      d2u[p] = u;
      const unsigned long long kk = ((unsigned long long)u << 32) | (unsigned)p;
      if      (kk < best)  { second = best; best = kk; }
      else if (kk < second){ second = kk; }
    }
    __syncthreads();

    for (int it = 0; it < K2NN; ++it){
      const unsigned vb = (unsigned)(best >> 32);
      const unsigned wv = wave_min_u32_sgpr(vb);
      const unsigned long long bal = __ballot(vb == wv);
      unsigned long long k;
      if (__popcll(bal) == 1){
        const int wl = __ffsll(bal) - 1;
        const unsigned lp = (unsigned)__builtin_amdgcn_readlane((int)(unsigned)best, wl);
        k = ((unsigned long long)wv << 32) | lp;     // low32 = p
      } else {
        // exact fallback: u64 (value,idx) min butterfly (rare value tie in wave)
        k = best;
        #pragma unroll
        for (int o = 32; o > 0; o >>= 1){
          const unsigned long long k2 = __shfl_xor(k, o);
          if (k2 < k) k = k2;
        }
      }
      if ((tid & 63) == 0) warr[it & 1][tid >> 6] = k;
      __syncthreads();
      unsigned long long kb = warr[it & 1][0];
      #pragma unroll
      for (int w = 1; w < 4; ++w){
        const unsigned long long k2 = warr[it & 1][w];
        if (k2 < kb) kb = k2;                        // u64 min: ties pick min p
      }
      const unsigned p = (unsigned)kb;
      if (tid == 0) nidx[it] = (int)p;
      if (best == kb){                               // unique owner (keys unique by p)
        d2u[p] = 0xFFFFFFFFu;                        // mark removed (own partition)
        best = second; second = ~0ULL;
        if (best == ~0ULL){                          // top-2 exhausted: rescan own part
          #pragma unroll 4
          for (int j = 0; j < NPTS/256; ++j){
            const int q = tid + 256*j;
            const unsigned long long kk = ((unsigned long long)d2u[q] << 32) | (unsigned)q;
            if      (kk < best)  { second = best; best = kk; }
            else if (kk < second){ second = kk; }
          }
        }
      }
    }
    __syncthreads();   // nidx complete; d2u dead from here (s1/s2 may alias)
  }

  // ================= Phase B: gather + EGNN ===============================
  const int ci = ws_idx[b*MCENT + m];
  if (tid < NC) hi[tid] = feat[((size_t)b*NC + tid)*NPTS + ci];
  if (tid < K2NN){
    const int p = nidx[tid];
    const float rx = cx - P[p*3+0];
    const float ry = cy - P[p*3+1];
    const float rz = cz - P[p*3+2];
    rel[tid][0]=rx; rel[tid][1]=ry; rel[tid][2]=rz;
    d2s[tid] = rx*rx + ry*ry + rz*rz;
  }
  {
    const int j  = tid >> 3;
    const int c0 = (tid & 7) * 8;
    const int p  = nidx[j];
    #pragma unroll
    for (int q = 0; q < 8; ++q)
      hj[j][c0+q] = feat[((size_t)b*NC + c0 + q)*NPTS + p];
  }
  __syncthreads();

  egnn_scale<16>(0, b, m, tid, we1, be1, we2, be2, wxw, bxw, wh1, bh1, wh2, bh2,
                 hi, hj, rel, d2s, s1, s2, coefs, aggs, t1, cx, cy, cz, out);
  egnn_scale<32>(1, b, m, tid, we1, be1, we2, be2, wxw, bxw, wh1, bh1, wh2, bh2,
                 hi, hj, rel, d2s, s1, s2, coefs, aggs, t1, cx, cy, cz, out);
}

// ---------------------------------------------------------------------------
extern "C" void kernel_launch(void* const* d_in, const int* in_sizes, int n_in,
                              void* d_out, int out_size, void* d_ws, size_t ws_size,
                              hipStream_t stream){
  const float* xyz = (const float*)d_in[0];
  const float* feat= (const float*)d_in[1];
  const float* we1 = (const float*)d_in[2];
  const float* be1 = (const float*)d_in[3];
  const float* we2 = (const float*)d_in[4];
  const float* be2 = (const float*)d_in[5];
  const float* wxw = (const float*)d_in[6];
  const float* bxw = (const float*)d_in[7];
  const float* wh1 = (const float*)d_in[8];
  const float* bh1 = (const float*)d_in[9];
  const float* wh2 = (const float*)d_in[10];
  const float* bh2 = (const float*)d_in[11];
  float* out = (float*)d_out;

  int* ws_idx = (int*)d_ws;   // B*M ints

  fps_kernel     <<<dim3(NB),       dim3(256), 0, stream>>>(xyz, out, ws_idx);
  knn_egnn_kernel<<<dim3(NB*MCENT), dim3(256), 0, stream>>>(xyz, feat,
      we1, be1, we2, be2, wxw, bxw, wh1, bh1, wh2, bh2, ws_idx, out);
}